// Round 1
// baseline (10851.118 us; speedup 1.0000x reference)
//
#include <hip/hip_runtime.h>
#include <hip/hip_bf16.h>

// ---------------------------------------------------------------------------
// 2-layer GraphSAGE on MI355X.
// Pipeline per launch (all on `stream`, graph-capture safe):
//   1. memset deg=0
//   2. k_deg      : atomic degree count by dst
//   3. k_scan     : single-block exclusive scan (shfl-based) -> offsets,
//                   cursor copy, inv_deg = 1/max(deg,1)
//   4. k_scatter  : CSR edge scatter (sorted src list per dst)
//   5. k_agg(x)   : per-node mean aggregation -> agg  (gather, no atomics)
//   6. k_gemm<128>: h1 = [x||agg] @ [Ws1;Wn1] + b1 -> out1 (h1), out2 (relu)
//   7. k_agg(h1r) : aggregation of relu(h1) -> agg
//   8. k_gemm<64> : h2 = [h1r||agg] @ [Ws2;Wn2] + b2 -> out0, out3
// ---------------------------------------------------------------------------

#define NFEAT 128

__global__ __launch_bounds__(256) void k_deg(const int* __restrict__ dst,
                                             int* __restrict__ deg, int E) {
    int e = blockIdx.x * 256 + threadIdx.x;
    if (e < E) atomicAdd(&deg[dst[e]], 1);
}

__global__ __launch_bounds__(1024) void k_scan(const int* __restrict__ deg,
                                               int* __restrict__ offsets,
                                               int* __restrict__ cursor,
                                               float* __restrict__ inv_deg,
                                               int n) {
    __shared__ int wsum[16];
    __shared__ int sbase;
    int tid = threadIdx.x;
    int lane = tid & 63, wid = tid >> 6;
    if (tid == 0) sbase = 0;
    __syncthreads();
    for (int start = 0; start < n; start += 1024) {
        int i = start + tid;
        int v = (i < n) ? deg[i] : 0;
        // wave-inclusive scan
        int incl = v;
        #pragma unroll
        for (int off = 1; off < 64; off <<= 1) {
            int t = __shfl_up(incl, off, 64);
            if (lane >= off) incl += t;
        }
        if (lane == 63) wsum[wid] = incl;
        __syncthreads();
        if (wid == 0) {
            int s = (lane < 16) ? wsum[lane] : 0;
            int si = s;
            #pragma unroll
            for (int off = 1; off < 16; off <<= 1) {
                int t = __shfl_up(si, off, 64);
                if (lane >= off) si += t;
            }
            if (lane < 16) wsum[lane] = si - s;  // exclusive prefix of wave sums
        }
        __syncthreads();
        int base = sbase;
        int excl = base + wsum[wid] + (incl - v);
        if (i < n) {
            offsets[i] = excl;
            cursor[i]  = excl;
            inv_deg[i] = 1.0f / fmaxf((float)v, 1.0f);
        }
        __syncthreads();
        if (tid == 1023) sbase = excl + v;  // running total
        __syncthreads();
    }
    if (threadIdx.x == 0) offsets[n] = sbase;
}

__global__ __launch_bounds__(256) void k_scatter(const int* __restrict__ src,
                                                 const int* __restrict__ dst,
                                                 int* __restrict__ cursor,
                                                 int* __restrict__ ssrc, int E) {
    int e = blockIdx.x * 256 + threadIdx.x;
    if (e < E) {
        int pos = atomicAdd(&cursor[dst[e]], 1);
        ssrc[pos] = src[e];
    }
}

// mean aggregation: one node per 32 lanes (float4 per lane covers 128 feats)
__global__ __launch_bounds__(256) void k_agg(const float* __restrict__ feat,
                                             const int* __restrict__ offs,
                                             const int* __restrict__ ssrc,
                                             const float* __restrict__ invd,
                                             float* __restrict__ agg, int n) {
    int node = blockIdx.x * 8 + (threadIdx.x >> 5);
    if (node >= n) return;
    int lane = threadIdx.x & 31;
    int beg = offs[node], end = offs[node + 1];
    float4 acc = make_float4(0.f, 0.f, 0.f, 0.f);
    for (int e = beg; e < end; ++e) {
        int s = ssrc[e];
        float4 v = *(const float4*)(feat + (size_t)s * NFEAT + lane * 4);
        acc.x += v.x; acc.y += v.y; acc.z += v.z; acc.w += v.w;
    }
    float iv = invd[node];
    float4 r = make_float4(acc.x * iv, acc.y * iv, acc.z * iv, acc.w * iv);
    *(float4*)(agg + (size_t)node * NFEAT + lane * 4) = r;
}

// C[M][NOUT] = [A0||A1] @ [W0;W1] + bias ; A0/A1 are [M][128], W are [128][NOUT]
// out_a gets raw value, out_b gets relu(value) if apply_relu else raw value.
template <int NOUT>
__global__ __launch_bounds__(256) void k_gemm(const float* __restrict__ A0,
                                              const float* __restrict__ A1,
                                              const float* __restrict__ W0,
                                              const float* __restrict__ W1,
                                              const float* __restrict__ bias,
                                              float* __restrict__ out_a,
                                              float* __restrict__ out_b,
                                              int M, int apply_relu) {
    constexpr int CW = NOUT / 16;   // cols per thread: 8 (NOUT=128) or 4 (64)
    constexpr int ASTRIDE = 36;     // 64-row tile, padded (mult of 4, %32==4)
    __shared__ float A_lds[64 * ASTRIDE];
    __shared__ float W_lds[32 * NOUT];

    int tid = threadIdx.x;
    int r0 = (tid >> 4) * 4;        // 16 row-groups of 4
    int c0 = (tid & 15) * CW;       // 16 col-groups
    int blockRow = blockIdx.x * 64;

    float acc[4][CW];
    #pragma unroll
    for (int i = 0; i < 4; ++i)
        #pragma unroll
        for (int j = 0; j < CW; ++j) acc[i][j] = 0.f;

    #pragma unroll
    for (int kc = 0; kc < 8; ++kc) {
        int k0 = kc * 32;
        const float* Asrc = (k0 < 128) ? A0 : A1;
        const float* Wsrc = (k0 < 128) ? W0 : W1;
        int kbase = k0 & 127;

        // stage A tile: 64 rows x 32 k (2 float4 per thread)
        #pragma unroll
        for (int it = 0; it < 2; ++it) {
            int lin = tid + it * 256;
            int nrow = lin >> 3;
            int kq = (lin & 7) * 4;
            float4 v = make_float4(0.f, 0.f, 0.f, 0.f);
            int row = blockRow + nrow;
            if (row < M)
                v = *(const float4*)(Asrc + (size_t)row * NFEAT + kbase + kq);
            *(float4*)(&A_lds[nrow * ASTRIDE + kq]) = v;
        }
        // stage W tile: 32 k x NOUT
        #pragma unroll
        for (int it = 0; it < (32 * NOUT / 4 / 256); ++it) {
            int lin = tid + it * 256;
            int kr = lin / (NOUT / 4);
            int cq = (lin % (NOUT / 4)) * 4;
            float4 v = *(const float4*)(Wsrc + (size_t)(kbase + kr) * NOUT + cq);
            *(float4*)(&W_lds[kr * NOUT + cq]) = v;
        }
        __syncthreads();

        #pragma unroll
        for (int kk = 0; kk < 32; ++kk) {
            float a[4];
            #pragma unroll
            for (int i = 0; i < 4; ++i) a[i] = A_lds[(r0 + i) * ASTRIDE + kk];
            float w[CW];
            #pragma unroll
            for (int j = 0; j < CW; ++j) w[j] = W_lds[kk * NOUT + c0 + j];
            #pragma unroll
            for (int i = 0; i < 4; ++i)
                #pragma unroll
                for (int j = 0; j < CW; ++j)
                    acc[i][j] = fmaf(a[i], w[j], acc[i][j]);
        }
        __syncthreads();
    }

    #pragma unroll
    for (int i = 0; i < 4; ++i) {
        int row = blockRow + r0 + i;
        if (row >= M) continue;
        #pragma unroll
        for (int j = 0; j < CW; ++j) {
            float val = acc[i][j] + bias[c0 + j];
            size_t idx = (size_t)row * NOUT + c0 + j;
            out_a[idx] = val;
            out_b[idx] = apply_relu ? fmaxf(val, 0.f) : val;
        }
    }
}

static inline size_t align256(size_t x) { return (x + 255) & ~(size_t)255; }

extern "C" void kernel_launch(void* const* d_in, const int* in_sizes, int n_in,
                              void* d_out, int out_size, void* d_ws, size_t ws_size,
                              hipStream_t stream) {
    const float* x   = (const float*)d_in[0];
    const float* Ws1 = (const float*)d_in[1];
    const float* Wn1 = (const float*)d_in[2];
    const float* b1  = (const float*)d_in[3];
    const float* Ws2 = (const float*)d_in[4];
    const float* Wn2 = (const float*)d_in[5];
    const float* b2  = (const float*)d_in[6];
    const int* src   = (const int*)d_in[7];
    const int* dst   = (const int*)d_in[8];

    int E = in_sizes[7];
    int N = in_sizes[0] / NFEAT;

    float* out = (float*)d_out;
    float* h2a = out;                         // h2 (copy 1), N x 64
    float* h1  = out + (size_t)N * 64;        // h1, N x 128
    float* h1r = out + (size_t)N * 192;       // relu(h1), N x 128
    float* h2b = out + (size_t)N * 320;       // h2 (copy 2), N x 64

    char* ws = (char*)d_ws;
    size_t off = 0;
    int*   deg    = (int*)(ws + off);  off = align256(off + (size_t)4 * N);
    int*   offs   = (int*)(ws + off);  off = align256(off + (size_t)4 * (N + 1));
    int*   cursor = (int*)(ws + off);  off = align256(off + (size_t)4 * N);
    float* invd   = (float*)(ws + off); off = align256(off + (size_t)4 * N);
    int*   ssrc   = (int*)(ws + off);  off = align256(off + (size_t)4 * E);
    float* agg    = (float*)(ws + off); off += (size_t)N * NFEAT * 4;

    hipMemsetAsync(deg, 0, (size_t)4 * N, stream);
    k_deg<<<(E + 255) / 256, 256, 0, stream>>>(dst, deg, E);
    k_scan<<<1, 1024, 0, stream>>>(deg, offs, cursor, invd, N);
    k_scatter<<<(E + 255) / 256, 256, 0, stream>>>(src, dst, cursor, ssrc, E);

    k_agg<<<(N + 7) / 8, 256, 0, stream>>>(x, offs, ssrc, invd, agg, N);
    k_gemm<128><<<(N + 63) / 64, 256, 0, stream>>>(x, agg, Ws1, Wn1, b1, h1, h1r, N, 1);

    k_agg<<<(N + 7) / 8, 256, 0, stream>>>(h1r, offs, ssrc, invd, agg, N);
    k_gemm<64><<<(N + 63) / 64, 256, 0, stream>>>(h1r, agg, Ws2, Wn2, b2, h2a, h2b, N, 0);
}

// Round 2
// 869.887 us; speedup vs baseline: 12.4742x; 12.4742x over previous
//
#include <hip/hip_runtime.h>
#include <hip/hip_bf16.h>

// ---------------------------------------------------------------------------
// 2-layer GraphSAGE on MI355X.
// Round 2: rewrote k_gemm. Round-1 version fully unrolled the K-loop (8192
// straight-line FMAs) -> 256 VGPRs + scratch spills (10.7 GB HBM traffic,
// VALUBusy 0.8%, 7 ms). New GEMM: 128xNOUT block tile, 8x8 per thread,
// K staged in 16-wide chunks with A transposed in LDS; chunk loop kept
// rolled (#pragma unroll 1) to bound code size / register pressure.
// ---------------------------------------------------------------------------

#define NFEAT 128

__global__ __launch_bounds__(256) void k_deg(const int* __restrict__ dst,
                                             int* __restrict__ deg, int E) {
    int e = blockIdx.x * 256 + threadIdx.x;
    if (e < E) atomicAdd(&deg[dst[e]], 1);
}

__global__ __launch_bounds__(1024) void k_scan(const int* __restrict__ deg,
                                               int* __restrict__ offsets,
                                               int* __restrict__ cursor,
                                               float* __restrict__ inv_deg,
                                               int n) {
    __shared__ int wsum[16];
    __shared__ int sbase;
    int tid = threadIdx.x;
    int lane = tid & 63, wid = tid >> 6;
    if (tid == 0) sbase = 0;
    __syncthreads();
    for (int start = 0; start < n; start += 1024) {
        int i = start + tid;
        int v = (i < n) ? deg[i] : 0;
        int incl = v;
        #pragma unroll
        for (int off = 1; off < 64; off <<= 1) {
            int t = __shfl_up(incl, off, 64);
            if (lane >= off) incl += t;
        }
        if (lane == 63) wsum[wid] = incl;
        __syncthreads();
        if (wid == 0) {
            int s = (lane < 16) ? wsum[lane] : 0;
            int si = s;
            #pragma unroll
            for (int off = 1; off < 16; off <<= 1) {
                int t = __shfl_up(si, off, 64);
                if (lane >= off) si += t;
            }
            if (lane < 16) wsum[lane] = si - s;
        }
        __syncthreads();
        int base = sbase;
        int excl = base + wsum[wid] + (incl - v);
        if (i < n) {
            offsets[i] = excl;
            cursor[i]  = excl;
            inv_deg[i] = 1.0f / fmaxf((float)v, 1.0f);
        }
        __syncthreads();
        if (tid == 1023) sbase = excl + v;
        __syncthreads();
    }
    if (threadIdx.x == 0) offsets[n] = sbase;
}

__global__ __launch_bounds__(256) void k_scatter(const int* __restrict__ src,
                                                 const int* __restrict__ dst,
                                                 int* __restrict__ cursor,
                                                 int* __restrict__ ssrc, int E) {
    int e = blockIdx.x * 256 + threadIdx.x;
    if (e < E) {
        int pos = atomicAdd(&cursor[dst[e]], 1);
        ssrc[pos] = src[e];
    }
}

// mean aggregation: one node per 32 lanes (float4 per lane covers 128 feats)
__global__ __launch_bounds__(256) void k_agg(const float* __restrict__ feat,
                                             const int* __restrict__ offs,
                                             const int* __restrict__ ssrc,
                                             const float* __restrict__ invd,
                                             float* __restrict__ agg, int n) {
    int node = blockIdx.x * 8 + (threadIdx.x >> 5);
    if (node >= n) return;
    int lane = threadIdx.x & 31;
    int beg = offs[node], end = offs[node + 1];
    float4 acc = make_float4(0.f, 0.f, 0.f, 0.f);
    for (int e = beg; e < end; ++e) {
        int s = ssrc[e];
        float4 v = *(const float4*)(feat + (size_t)s * NFEAT + lane * 4);
        acc.x += v.x; acc.y += v.y; acc.z += v.z; acc.w += v.w;
    }
    float iv = invd[node];
    float4 r = make_float4(acc.x * iv, acc.y * iv, acc.z * iv, acc.w * iv);
    *(float4*)(agg + (size_t)node * NFEAT + lane * 4) = r;
}

// C[M][NOUT] = [A0||A1] @ [W0;W1] + bias; A0/A1: [M][128] row-major,
// W0/W1: [128][NOUT] row-major. out_a = raw, out_b = relu? relu(raw) : raw.
// Block: 128 rows x NOUT cols, 256 threads, 8 rows x (NOUT/16) cols each.
template <int NOUT>
__global__ __launch_bounds__(256) void k_gemm(const float* __restrict__ A0,
                                              const float* __restrict__ A1,
                                              const float* __restrict__ W0,
                                              const float* __restrict__ W1,
                                              const float* __restrict__ bias,
                                              float* __restrict__ out_a,
                                              float* __restrict__ out_b,
                                              int M, int apply_relu) {
    constexpr int RW = 8;
    constexpr int CW = NOUT / 16;     // 8 (layer1) or 4 (layer2)
    constexpr int ASTR = 132;         // A^T LDS stride (pad breaks 128-alias)
    __shared__ float A_lds[16 * ASTR];   // A^T chunk: [k 0..15][row 0..127]
    __shared__ float W_lds[16 * NOUT];   // W chunk:   [k 0..15][col]

    int tid = threadIdx.x;
    int r0 = (tid & 15) * RW;
    int c0 = (tid >> 4) * CW;
    long blockRow = (long)blockIdx.x * 128;

    float acc[RW][CW];
    #pragma unroll
    for (int i = 0; i < RW; ++i)
        #pragma unroll
        for (int j = 0; j < CW; ++j) acc[i][j] = 0.f;

    for (int h = 0; h < 2; ++h) {
        const float* __restrict__ A = h ? A1 : A0;
        const float* __restrict__ W = h ? W1 : W0;
        #pragma unroll 1
        for (int kc = 0; kc < 8; ++kc) {
            int kbase = kc * 16;
            // stage A chunk (128 rows x 16 k), transposed into LDS
            #pragma unroll
            for (int it = 0; it < 2; ++it) {
                int lin = tid + it * 256;      // 0..511
                int row = lin >> 2;            // 0..127
                int kq  = (lin & 3) * 4;       // 0,4,8,12
                long grow = blockRow + row;
                float4 v = make_float4(0.f, 0.f, 0.f, 0.f);
                if (grow < M)
                    v = *(const float4*)(A + grow * NFEAT + kbase + kq);
                A_lds[(kq + 0) * ASTR + row] = v.x;
                A_lds[(kq + 1) * ASTR + row] = v.y;
                A_lds[(kq + 2) * ASTR + row] = v.z;
                A_lds[(kq + 3) * ASTR + row] = v.w;
            }
            // stage W chunk (16 k x NOUT), layout preserved
            #pragma unroll
            for (int it = 0; it < (16 * NOUT / 4) / 256; ++it) {
                int lin = tid + it * 256;
                int kr = lin / (NOUT / 4);
                int cq = (lin % (NOUT / 4)) * 4;
                *(float4*)&W_lds[kr * NOUT + cq] =
                    *(const float4*)(W + (size_t)(kbase + kr) * NOUT + cq);
            }
            __syncthreads();

            #pragma unroll
            for (int kk = 0; kk < 16; ++kk) {
                float a[RW], w[CW];
                *(float4*)&a[0] = *(const float4*)&A_lds[kk * ASTR + r0];
                *(float4*)&a[4] = *(const float4*)&A_lds[kk * ASTR + r0 + 4];
                *(float4*)&w[0] = *(const float4*)&W_lds[kk * NOUT + c0];
                if (CW == 8)
                    *(float4*)&w[4] = *(const float4*)&W_lds[kk * NOUT + c0 + 4];
                #pragma unroll
                for (int i = 0; i < RW; ++i)
                    #pragma unroll
                    for (int j = 0; j < CW; ++j)
                        acc[i][j] = fmaf(a[i], w[j], acc[i][j]);
            }
            __syncthreads();
        }
    }

    float bv[CW];
    #pragma unroll
    for (int j = 0; j < CW; ++j) bv[j] = bias[c0 + j];

    #pragma unroll
    for (int i = 0; i < RW; ++i) {
        long row = blockRow + r0 + i;
        if (row >= M) continue;
        float va[CW], vb[CW];
        #pragma unroll
        for (int j = 0; j < CW; ++j) {
            float val = acc[i][j] + bv[j];
            va[j] = val;
            vb[j] = apply_relu ? fmaxf(val, 0.f) : val;
        }
        size_t idx = (size_t)row * NOUT + c0;
        #pragma unroll
        for (int q = 0; q < CW / 4; ++q) {
            *(float4*)(out_a + idx + q * 4) = *(float4*)&va[q * 4];
            *(float4*)(out_b + idx + q * 4) = *(float4*)&vb[q * 4];
        }
    }
}

static inline size_t align256(size_t x) { return (x + 255) & ~(size_t)255; }

extern "C" void kernel_launch(void* const* d_in, const int* in_sizes, int n_in,
                              void* d_out, int out_size, void* d_ws, size_t ws_size,
                              hipStream_t stream) {
    const float* x   = (const float*)d_in[0];
    const float* Ws1 = (const float*)d_in[1];
    const float* Wn1 = (const float*)d_in[2];
    const float* b1  = (const float*)d_in[3];
    const float* Ws2 = (const float*)d_in[4];
    const float* Wn2 = (const float*)d_in[5];
    const float* b2  = (const float*)d_in[6];
    const int* src   = (const int*)d_in[7];
    const int* dst   = (const int*)d_in[8];

    int E = in_sizes[7];
    int N = in_sizes[0] / NFEAT;

    float* out = (float*)d_out;
    float* h2a = out;                         // h2 (copy 1), N x 64
    float* h1  = out + (size_t)N * 64;        // h1, N x 128
    float* h1r = out + (size_t)N * 192;       // relu(h1), N x 128
    float* h2b = out + (size_t)N * 320;       // h2 (copy 2), N x 64

    char* ws = (char*)d_ws;
    size_t off = 0;
    int*   deg    = (int*)(ws + off);  off = align256(off + (size_t)4 * N);
    int*   offs   = (int*)(ws + off);  off = align256(off + (size_t)4 * (N + 1));
    int*   cursor = (int*)(ws + off);  off = align256(off + (size_t)4 * N);
    float* invd   = (float*)(ws + off); off = align256(off + (size_t)4 * N);
    int*   ssrc   = (int*)(ws + off);  off = align256(off + (size_t)4 * E);
    float* agg    = (float*)(ws + off); off += (size_t)N * NFEAT * 4;

    hipMemsetAsync(deg, 0, (size_t)4 * N, stream);
    k_deg<<<(E + 255) / 256, 256, 0, stream>>>(dst, deg, E);
    k_scan<<<1, 1024, 0, stream>>>(deg, offs, cursor, invd, N);
    k_scatter<<<(E + 255) / 256, 256, 0, stream>>>(src, dst, cursor, ssrc, E);

    k_agg<<<(N + 7) / 8, 256, 0, stream>>>(x, offs, ssrc, invd, agg, N);
    k_gemm<128><<<(N + 127) / 128, 256, 0, stream>>>(x, agg, Ws1, Wn1, b1, h1, h1r, N, 1);

    k_agg<<<(N + 7) / 8, 256, 0, stream>>>(h1r, offs, ssrc, invd, agg, N);
    k_gemm<64><<<(N + 127) / 128, 256, 0, stream>>>(h1r, agg, Ws2, Wn2, b2, h2a, h2b, N, 0);
}

// Round 3
// 705.515 us; speedup vs baseline: 15.3804x; 1.2330x over previous
//
#include <hip/hip_runtime.h>
#include <hip/hip_bf16.h>

// ---------------------------------------------------------------------------
// 2-layer GraphSAGE on MI355X. Round 3.
//   - Layer-2 restructure: p2 = h1r @ Wn2 computed FIRST (N x 64), then
//     aggregated (linear op commutes with mean aggregation) -> half the
//     gather width for layer 2.
//   - Gather payloads in bf16: x -> xb (bf16), p2 stored as bf16. Gather
//     traffic halves again; accumulation stays fp32.
//   - Multi-block 3-kernel scan replaces the single-block 98-iteration scan.
// Pipeline: memset deg -> k_deg -> scan1/2/3 -> k_cvt -> k_scatter ->
//   k_agg1(xb) -> k_gemm<128>([x||agg]) -> k_gemm2(h1r -> s2,p2b) ->
//   k_agg2(p2b, s2 -> h2a,h2b)
// ---------------------------------------------------------------------------

#define NFEAT 128

static __device__ inline unsigned short f2bf(float f) {
    union { float f; unsigned int u; } v; v.f = f;
    unsigned int u = v.u;
    unsigned int r = (u + 0x7FFFu + ((u >> 16) & 1u)) >> 16;   // RNE
    return (unsigned short)r;
}
static __device__ inline float bf2f(unsigned short h) {
    union { unsigned int u; float f; } v; v.u = ((unsigned int)h) << 16;
    return v.f;
}

__global__ __launch_bounds__(256) void k_deg(const int* __restrict__ dst,
                                             int* __restrict__ deg, int E) {
    int e = blockIdx.x * 256 + threadIdx.x;
    if (e < E) atomicAdd(&deg[dst[e]], 1);
}

// ---- 3-kernel scan: deg -> offs/cursor/invd --------------------------------
__global__ __launch_bounds__(256) void k_scan1(const int* __restrict__ deg,
                                               int* __restrict__ escan,
                                               int* __restrict__ bsum, int n) {
    __shared__ int ws4[4];
    int tid = threadIdx.x;
    int base = blockIdx.x * 1024 + tid * 4;
    int d[4];
    #pragma unroll
    for (int j = 0; j < 4; ++j) d[j] = (base + j < n) ? deg[base + j] : 0;
    int s = d[0] + d[1] + d[2] + d[3];
    int lane = tid & 63, wid = tid >> 6;
    int incl = s;
    #pragma unroll
    for (int off = 1; off < 64; off <<= 1) {
        int t = __shfl_up(incl, off, 64);
        if (lane >= off) incl += t;
    }
    if (lane == 63) ws4[wid] = incl;
    __syncthreads();
    int wbase = 0;
    #pragma unroll
    for (int w = 0; w < 4; ++w) if (w < wid) wbase += ws4[w];
    int run = wbase + incl - s;
    #pragma unroll
    for (int j = 0; j < 4; ++j) {
        if (base + j < n) escan[base + j] = run;
        run += d[j];
    }
    if (tid == 255) bsum[blockIdx.x] = run;
}

__global__ __launch_bounds__(1024) void k_scan2(int* __restrict__ bsum, int nb) {
    __shared__ int ws16[16];
    int tid = threadIdx.x;
    int lane = tid & 63, wid = tid >> 6;
    int v = (tid < nb) ? bsum[tid] : 0;
    int incl = v;
    #pragma unroll
    for (int off = 1; off < 64; off <<= 1) {
        int t = __shfl_up(incl, off, 64);
        if (lane >= off) incl += t;
    }
    if (lane == 63) ws16[wid] = incl;
    __syncthreads();
    int wbase = 0;
    for (int w = 0; w < 16; ++w) if (w < wid) wbase += ws16[w];
    if (tid < nb) bsum[tid] = wbase + incl - v;   // exclusive
}

__global__ __launch_bounds__(256) void k_scan3(const int* __restrict__ deg,
                                               const int* __restrict__ escan,
                                               const int* __restrict__ bsum,
                                               int* __restrict__ offs,
                                               int* __restrict__ cursor,
                                               float* __restrict__ invd, int n) {
    int tid = threadIdx.x;
    int base = blockIdx.x * 1024 + tid * 4;
    int bb = bsum[blockIdx.x];
    #pragma unroll
    for (int j = 0; j < 4; ++j) {
        int i = base + j;
        if (i < n) {
            int d = deg[i];
            int off = escan[i] + bb;
            offs[i] = off;
            cursor[i] = off;
            invd[i] = 1.0f / fmaxf((float)d, 1.0f);
            if (i == n - 1) offs[n] = off + d;
        }
    }
}

// ---- x -> bf16 -------------------------------------------------------------
__global__ __launch_bounds__(256) void k_cvt(const float* __restrict__ x,
                                             unsigned short* __restrict__ xb,
                                             int total4) {
    int i = blockIdx.x * 256 + threadIdx.x;
    if (i >= total4) return;
    float4 v = *(const float4*)(x + (size_t)i * 4);
    ushort4 o;
    o.x = f2bf(v.x); o.y = f2bf(v.y); o.z = f2bf(v.z); o.w = f2bf(v.w);
    *(ushort4*)(xb + (size_t)i * 4) = o;
}

__global__ __launch_bounds__(256) void k_scatter(const int* __restrict__ src,
                                                 const int* __restrict__ dst,
                                                 int* __restrict__ cursor,
                                                 int* __restrict__ ssrc, int E) {
    int e = blockIdx.x * 256 + threadIdx.x;
    if (e < E) {
        int pos = atomicAdd(&cursor[dst[e]], 1);
        ssrc[pos] = src[e];
    }
}

// ---- layer-1 aggregation: gather bf16 x rows, mean -> agg (fp32, N x 128) --
__global__ __launch_bounds__(256) void k_agg1(const unsigned short* __restrict__ xb,
                                              const int* __restrict__ offs,
                                              const int* __restrict__ ssrc,
                                              const float* __restrict__ invd,
                                              float* __restrict__ agg, int n) {
    int node = blockIdx.x * 8 + (threadIdx.x >> 5);
    if (node >= n) return;
    int lane = threadIdx.x & 31;           // 32 lanes x 4 bf16 = 128 feats
    int beg = offs[node], end = offs[node + 1];
    float a0 = 0.f, a1 = 0.f, a2 = 0.f, a3 = 0.f;
    for (int e = beg; e < end; ++e) {
        int s = ssrc[e];
        ushort4 v = *(const ushort4*)(xb + (size_t)s * NFEAT + lane * 4);
        a0 += bf2f(v.x); a1 += bf2f(v.y); a2 += bf2f(v.z); a3 += bf2f(v.w);
    }
    float iv = invd[node];
    float4 r = make_float4(a0 * iv, a1 * iv, a2 * iv, a3 * iv);
    *(float4*)(agg + (size_t)node * NFEAT + lane * 4) = r;
}

// ---- layer-1 GEMM: [A0||A1] @ [W0;W1] + b -> h1, relu(h1) ------------------
template <int NOUT>
__global__ __launch_bounds__(256) void k_gemm(const float* __restrict__ A0,
                                              const float* __restrict__ A1,
                                              const float* __restrict__ W0,
                                              const float* __restrict__ W1,
                                              const float* __restrict__ bias,
                                              float* __restrict__ out_a,
                                              float* __restrict__ out_b,
                                              int M, int apply_relu) {
    constexpr int RW = 8;
    constexpr int CW = NOUT / 16;
    constexpr int ASTR = 132;
    __shared__ float A_lds[16 * ASTR];
    __shared__ float W_lds[16 * NOUT];

    int tid = threadIdx.x;
    int r0 = (tid & 15) * RW;
    int c0 = (tid >> 4) * CW;
    long blockRow = (long)blockIdx.x * 128;

    float acc[RW][CW];
    #pragma unroll
    for (int i = 0; i < RW; ++i)
        #pragma unroll
        for (int j = 0; j < CW; ++j) acc[i][j] = 0.f;

    for (int h = 0; h < 2; ++h) {
        const float* __restrict__ A = h ? A1 : A0;
        const float* __restrict__ W = h ? W1 : W0;
        #pragma unroll 1
        for (int kc = 0; kc < 8; ++kc) {
            int kbase = kc * 16;
            #pragma unroll
            for (int it = 0; it < 2; ++it) {
                int lin = tid + it * 256;
                int row = lin >> 2;
                int kq  = (lin & 3) * 4;
                long grow = blockRow + row;
                float4 v = make_float4(0.f, 0.f, 0.f, 0.f);
                if (grow < M)
                    v = *(const float4*)(A + grow * NFEAT + kbase + kq);
                A_lds[(kq + 0) * ASTR + row] = v.x;
                A_lds[(kq + 1) * ASTR + row] = v.y;
                A_lds[(kq + 2) * ASTR + row] = v.z;
                A_lds[(kq + 3) * ASTR + row] = v.w;
            }
            #pragma unroll
            for (int it = 0; it < (16 * NOUT / 4) / 256; ++it) {
                int lin = tid + it * 256;
                int kr = lin / (NOUT / 4);
                int cq = (lin % (NOUT / 4)) * 4;
                *(float4*)&W_lds[kr * NOUT + cq] =
                    *(const float4*)(W + (size_t)(kbase + kr) * NOUT + cq);
            }
            __syncthreads();

            #pragma unroll
            for (int kk = 0; kk < 16; ++kk) {
                float a[RW], w[CW];
                *(float4*)&a[0] = *(const float4*)&A_lds[kk * ASTR + r0];
                *(float4*)&a[4] = *(const float4*)&A_lds[kk * ASTR + r0 + 4];
                *(float4*)&w[0] = *(const float4*)&W_lds[kk * NOUT + c0];
                if (CW == 8)
                    *(float4*)&w[4] = *(const float4*)&W_lds[kk * NOUT + c0 + 4];
                #pragma unroll
                for (int i = 0; i < RW; ++i)
                    #pragma unroll
                    for (int j = 0; j < CW; ++j)
                        acc[i][j] = fmaf(a[i], w[j], acc[i][j]);
            }
            __syncthreads();
        }
    }

    float bv[CW];
    #pragma unroll
    for (int j = 0; j < CW; ++j) bv[j] = bias[c0 + j];

    #pragma unroll
    for (int i = 0; i < RW; ++i) {
        long row = blockRow + r0 + i;
        if (row >= M) continue;
        float va[CW], vb[CW];
        #pragma unroll
        for (int j = 0; j < CW; ++j) {
            float val = acc[i][j] + bv[j];
            va[j] = val;
            vb[j] = apply_relu ? fmaxf(val, 0.f) : val;
        }
        size_t idx = (size_t)row * NOUT + c0;
        #pragma unroll
        for (int q = 0; q < CW / 4; ++q) {
            *(float4*)(out_a + idx + q * 4) = *(float4*)&va[q * 4];
            *(float4*)(out_b + idx + q * 4) = *(float4*)&vb[q * 4];
        }
    }
}

// ---- layer-2 GEMM: s2 = A @ Ws (fp32), p2 = A @ Wn (bf16); A = h1r [M][128]
__global__ __launch_bounds__(256) void k_gemm2(const float* __restrict__ A,
                                               const float* __restrict__ Ws,
                                               const float* __restrict__ Wn,
                                               float* __restrict__ s2,
                                               unsigned short* __restrict__ p2b,
                                               int M) {
    constexpr int RW = 8, CW = 4, NO = 64;
    constexpr int ASTR = 132;
    __shared__ float A_lds[16 * ASTR];
    __shared__ float Ws_lds[16 * NO];
    __shared__ float Wn_lds[16 * NO];

    int tid = threadIdx.x;
    int r0 = (tid & 15) * RW;
    int c0 = (tid >> 4) * CW;
    long blockRow = (long)blockIdx.x * 128;

    float accS[RW][CW], accP[RW][CW];
    #pragma unroll
    for (int i = 0; i < RW; ++i)
        #pragma unroll
        for (int j = 0; j < CW; ++j) { accS[i][j] = 0.f; accP[i][j] = 0.f; }

    #pragma unroll 1
    for (int kc = 0; kc < 8; ++kc) {
        int kbase = kc * 16;
        #pragma unroll
        for (int it = 0; it < 2; ++it) {
            int lin = tid + it * 256;
            int row = lin >> 2;
            int kq  = (lin & 3) * 4;
            long grow = blockRow + row;
            float4 v = make_float4(0.f, 0.f, 0.f, 0.f);
            if (grow < M)
                v = *(const float4*)(A + grow * NFEAT + kbase + kq);
            A_lds[(kq + 0) * ASTR + row] = v.x;
            A_lds[(kq + 1) * ASTR + row] = v.y;
            A_lds[(kq + 2) * ASTR + row] = v.z;
            A_lds[(kq + 3) * ASTR + row] = v.w;
        }
        {   // 16 x 64 each, 256 float4 -> one iter per matrix
            int kr = tid >> 4;           // 0..15
            int cq = (tid & 15) * 4;     // 0..60
            *(float4*)&Ws_lds[kr * NO + cq] =
                *(const float4*)(Ws + (size_t)(kbase + kr) * NO + cq);
            *(float4*)&Wn_lds[kr * NO + cq] =
                *(const float4*)(Wn + (size_t)(kbase + kr) * NO + cq);
        }
        __syncthreads();

        #pragma unroll
        for (int kk = 0; kk < 16; ++kk) {
            float a[RW], ws[CW], wp[CW];
            *(float4*)&a[0] = *(const float4*)&A_lds[kk * ASTR + r0];
            *(float4*)&a[4] = *(const float4*)&A_lds[kk * ASTR + r0 + 4];
            *(float4*)&ws[0] = *(const float4*)&Ws_lds[kk * NO + c0];
            *(float4*)&wp[0] = *(const float4*)&Wn_lds[kk * NO + c0];
            #pragma unroll
            for (int i = 0; i < RW; ++i)
                #pragma unroll
                for (int j = 0; j < CW; ++j) {
                    accS[i][j] = fmaf(a[i], ws[j], accS[i][j]);
                    accP[i][j] = fmaf(a[i], wp[j], accP[i][j]);
                }
        }
        __syncthreads();
    }

    #pragma unroll
    for (int i = 0; i < RW; ++i) {
        long row = blockRow + r0 + i;
        if (row >= M) continue;
        *(float4*)(s2 + (size_t)row * NO + c0) = *(float4*)&accS[i][0];
        ushort4 o;
        o.x = f2bf(accP[i][0]); o.y = f2bf(accP[i][1]);
        o.z = f2bf(accP[i][2]); o.w = f2bf(accP[i][3]);
        *(ushort4*)(p2b + (size_t)row * NO + c0) = o;
    }
}

// ---- layer-2 aggregation + epilogue: h2 = s2 + inv*sum(p2b[src]) + b2 ------
__global__ __launch_bounds__(256) void k_agg2(const unsigned short* __restrict__ p2b,
                                              const int* __restrict__ offs,
                                              const int* __restrict__ ssrc,
                                              const float* __restrict__ invd,
                                              const float* __restrict__ s2,
                                              const float* __restrict__ b2,
                                              float* __restrict__ h2a,
                                              float* __restrict__ h2b, int n) {
    int node = blockIdx.x * 16 + (threadIdx.x >> 4);
    if (node >= n) return;
    int lane = threadIdx.x & 15;           // 16 lanes x 4 bf16 = 64 feats
    int beg = offs[node], end = offs[node + 1];
    float a0 = 0.f, a1 = 0.f, a2 = 0.f, a3 = 0.f;
    for (int e = beg; e < end; ++e) {
        int s = ssrc[e];
        ushort4 v = *(const ushort4*)(p2b + (size_t)s * 64 + lane * 4);
        a0 += bf2f(v.x); a1 += bf2f(v.y); a2 += bf2f(v.z); a3 += bf2f(v.w);
    }
    float iv = invd[node];
    float4 sv = *(const float4*)(s2 + (size_t)node * 64 + lane * 4);
    float4 bv = *(const float4*)(b2 + lane * 4);
    float4 r = make_float4(sv.x + a0 * iv + bv.x, sv.y + a1 * iv + bv.y,
                           sv.z + a2 * iv + bv.z, sv.w + a3 * iv + bv.w);
    *(float4*)(h2a + (size_t)node * 64 + lane * 4) = r;
    *(float4*)(h2b + (size_t)node * 64 + lane * 4) = r;
}

static inline size_t align256(size_t x) { return (x + 255) & ~(size_t)255; }

extern "C" void kernel_launch(void* const* d_in, const int* in_sizes, int n_in,
                              void* d_out, int out_size, void* d_ws, size_t ws_size,
                              hipStream_t stream) {
    const float* x   = (const float*)d_in[0];
    const float* Ws1 = (const float*)d_in[1];
    const float* Wn1 = (const float*)d_in[2];
    const float* b1  = (const float*)d_in[3];
    const float* Ws2 = (const float*)d_in[4];
    const float* Wn2 = (const float*)d_in[5];
    const float* b2  = (const float*)d_in[6];
    const int* src   = (const int*)d_in[7];
    const int* dst   = (const int*)d_in[8];

    int E = in_sizes[7];
    int N = in_sizes[0] / NFEAT;

    float* out = (float*)d_out;
    float* h2a = out;                         // h2 (copy 1), N x 64
    float* h1  = out + (size_t)N * 64;        // h1, N x 128
    float* h1r = out + (size_t)N * 192;       // relu(h1), N x 128
    float* h2b = out + (size_t)N * 320;       // h2 (copy 2), N x 64

    char* ws = (char*)d_ws;
    size_t off = 0;
    int*   deg    = (int*)(ws + off);  off = align256(off + (size_t)4 * N);
    int*   offs   = (int*)(ws + off);  off = align256(off + (size_t)4 * (N + 1));
    int*   cursor = (int*)(ws + off);  off = align256(off + (size_t)4 * N);
    float* invd   = (float*)(ws + off); off = align256(off + (size_t)4 * N);
    int*   escan  = (int*)(ws + off);  off = align256(off + (size_t)4 * N);
    int*   bsum   = (int*)(ws + off);  off = align256(off + (size_t)4 * 1024);
    int*   ssrc   = (int*)(ws + off);  off = align256(off + (size_t)4 * E);
    // region1: xb (N*128 bf16 = 25.6 MB) aliases s2 (N*64 f32 = 25.6 MB)
    unsigned short* xb = (unsigned short*)(ws + off);
    float*          s2 = (float*)(ws + off);
    off = align256(off + (size_t)N * NFEAT * 2);
    // region2: agg (N*128 f32 = 51.2 MB) aliases p2b (N*64 bf16 = 12.8 MB)
    float*          agg = (float*)(ws + off);
    unsigned short* p2b = (unsigned short*)(ws + off);
    off += (size_t)N * NFEAT * 4;

    int nb = (N + 1023) / 1024;

    hipMemsetAsync(deg, 0, (size_t)4 * N, stream);
    k_deg<<<(E + 255) / 256, 256, 0, stream>>>(dst, deg, E);
    k_scan1<<<nb, 256, 0, stream>>>(deg, escan, bsum, N);
    k_scan2<<<1, 1024, 0, stream>>>(bsum, nb);
    k_scan3<<<nb, 256, 0, stream>>>(deg, escan, bsum, offs, cursor, invd, N);
    k_cvt<<<(N * 32 + 255) / 256, 256, 0, stream>>>(x, xb, N * 32);
    k_scatter<<<(E + 255) / 256, 256, 0, stream>>>(src, dst, cursor, ssrc, E);

    k_agg1<<<(N + 7) / 8, 256, 0, stream>>>(xb, offs, ssrc, invd, agg, N);
    k_gemm<128><<<(N + 127) / 128, 256, 0, stream>>>(x, agg, Ws1, Wn1, b1, h1, h1r, N, 1);

    k_gemm2<<<(N + 127) / 128, 256, 0, stream>>>(h1r, Ws2, Wn2, s2, p2b, N);
    k_agg2<<<(N + 15) / 16, 256, 0, stream>>>(p2b, offs, ssrc, invd, s2, b2, h2a, h2b, N);
}

// Round 4
// 648.999 us; speedup vs baseline: 16.7198x; 1.0871x over previous
//
#include <hip/hip_runtime.h>
#include <hip/hip_bf16.h>

// ---------------------------------------------------------------------------
// 2-layer GraphSAGE on MI355X. Round 4: MFMA bf16 GEMMs.
//   - k_wprep1/2 pre-swizzle weights (fp32 -> bf16) into B-fragment-linear
//     layout: frag(ks,ct,lane) = W[ks*32+(lane>>4)*8+j][ct*16+(lane&15)],
//     stored as coalesced ushort8. All blocks stream it from L2.
//   - k_mm1: h1 = [xb||aggb] @ Wb1 + b1 via mfma_f32_16x16x32_bf16.
//     No LDS, no __syncthreads. A-frags loaded straight from global bf16.
//     Outputs h1 (f32), h1r (f32), h1rb (bf16, feeds layer 2).
//   - k_mm2: [s2|p2] = h1rb @ [Ws2|Wn2] (K=128); s2 f32, p2 bf16.
//   - k_agg1 now outputs bf16 (halves its write traffic; mm1 reads bf16).
//   - MFMA layouts per verified m89/m91/m120 mappings:
//     A: A[m=lane&15][k=(lane>>4)*8+j]; C/D: col=lane&15, row=(lane>>4)*4+i.
// ---------------------------------------------------------------------------

#define NFEAT 128

typedef __bf16 bf16x8 __attribute__((ext_vector_type(8)));
typedef float  f32x4  __attribute__((ext_vector_type(4)));

static __device__ inline unsigned short f2bf(float f) {
    union { float f; unsigned int u; } v; v.f = f;
    unsigned int u = v.u;
    unsigned int r = (u + 0x7FFFu + ((u >> 16) & 1u)) >> 16;   // RNE
    return (unsigned short)r;
}
static __device__ inline float bf2f(unsigned short h) {
    union { unsigned int u; float f; } v; v.u = ((unsigned int)h) << 16;
    return v.f;
}

__global__ __launch_bounds__(256) void k_deg(const int* __restrict__ dst,
                                             int* __restrict__ deg, int E) {
    int e = blockIdx.x * 256 + threadIdx.x;
    if (e < E) atomicAdd(&deg[dst[e]], 1);
}

// ---- 3-kernel scan ---------------------------------------------------------
__global__ __launch_bounds__(256) void k_scan1(const int* __restrict__ deg,
                                               int* __restrict__ escan,
                                               int* __restrict__ bsum, int n) {
    __shared__ int ws4[4];
    int tid = threadIdx.x;
    int base = blockIdx.x * 1024 + tid * 4;
    int d[4];
    #pragma unroll
    for (int j = 0; j < 4; ++j) d[j] = (base + j < n) ? deg[base + j] : 0;
    int s = d[0] + d[1] + d[2] + d[3];
    int lane = tid & 63, wid = tid >> 6;
    int incl = s;
    #pragma unroll
    for (int off = 1; off < 64; off <<= 1) {
        int t = __shfl_up(incl, off, 64);
        if (lane >= off) incl += t;
    }
    if (lane == 63) ws4[wid] = incl;
    __syncthreads();
    int wbase = 0;
    #pragma unroll
    for (int w = 0; w < 4; ++w) if (w < wid) wbase += ws4[w];
    int run = wbase + incl - s;
    #pragma unroll
    for (int j = 0; j < 4; ++j) {
        if (base + j < n) escan[base + j] = run;
        run += d[j];
    }
    if (tid == 255) bsum[blockIdx.x] = run;
}

__global__ __launch_bounds__(1024) void k_scan2(int* __restrict__ bsum, int nb) {
    __shared__ int ws16[16];
    int tid = threadIdx.x;
    int lane = tid & 63, wid = tid >> 6;
    int v = (tid < nb) ? bsum[tid] : 0;
    int incl = v;
    #pragma unroll
    for (int off = 1; off < 64; off <<= 1) {
        int t = __shfl_up(incl, off, 64);
        if (lane >= off) incl += t;
    }
    if (lane == 63) ws16[wid] = incl;
    __syncthreads();
    int wbase = 0;
    for (int w = 0; w < 16; ++w) if (w < wid) wbase += ws16[w];
    if (tid < nb) bsum[tid] = wbase + incl - v;   // exclusive
}

__global__ __launch_bounds__(256) void k_scan3(const int* __restrict__ deg,
                                               const int* __restrict__ escan,
                                               const int* __restrict__ bsum,
                                               int* __restrict__ offs,
                                               int* __restrict__ cursor,
                                               float* __restrict__ invd, int n) {
    int tid = threadIdx.x;
    int base = blockIdx.x * 1024 + tid * 4;
    int bb = bsum[blockIdx.x];
    #pragma unroll
    for (int j = 0; j < 4; ++j) {
        int i = base + j;
        if (i < n) {
            int d = deg[i];
            int off = escan[i] + bb;
            offs[i] = off;
            cursor[i] = off;
            invd[i] = 1.0f / fmaxf((float)d, 1.0f);
            if (i == n - 1) offs[n] = off + d;
        }
    }
}

// ---- x -> bf16 -------------------------------------------------------------
__global__ __launch_bounds__(256) void k_cvt(const float* __restrict__ x,
                                             unsigned short* __restrict__ xb,
                                             int total4) {
    int i = blockIdx.x * 256 + threadIdx.x;
    if (i >= total4) return;
    float4 v = *(const float4*)(x + (size_t)i * 4);
    ushort4 o;
    o.x = f2bf(v.x); o.y = f2bf(v.y); o.z = f2bf(v.z); o.w = f2bf(v.w);
    *(ushort4*)(xb + (size_t)i * 4) = o;
}

// ---- weight pre-swizzle into B-fragment-linear layout ----------------------
// wb[((ks*8+ct)*64+lane)*8 + j] = W[ks*32+(lane>>4)*8+j][ct*16+(lane&15)]
__global__ __launch_bounds__(256) void k_wprep1(const float* __restrict__ Ws,
                                                const float* __restrict__ Wn,
                                                unsigned short* __restrict__ wb) {
    int idx = blockIdx.x * 256 + threadIdx.x;        // 8*8*64*8 = 32768
    if (idx >= 32768) return;
    int j = idx & 7, lane = (idx >> 3) & 63, ct = (idx >> 9) & 7, ks = idx >> 12;
    int k = ks * 32 + ((lane >> 4) & 3) * 8 + j;     // 0..255
    int n = ct * 16 + (lane & 15);                   // 0..127
    float v = (k < 128) ? Ws[k * 128 + n] : Wn[(k - 128) * 128 + n];
    wb[idx] = f2bf(v);
}

__global__ __launch_bounds__(256) void k_wprep2(const float* __restrict__ Ws,
                                                const float* __restrict__ Wn,
                                                unsigned short* __restrict__ wb) {
    int idx = blockIdx.x * 256 + threadIdx.x;        // 4*8*64*8 = 16384
    if (idx >= 16384) return;
    int j = idx & 7, lane = (idx >> 3) & 63, ct = (idx >> 9) & 7, ks = idx >> 12;
    int k = ks * 32 + ((lane >> 4) & 3) * 8 + j;     // 0..127
    int n = ct * 16 + (lane & 15);                   // 0..127; <64 Ws, >=64 Wn
    float v = (n < 64) ? Ws[k * 64 + n] : Wn[k * 64 + (n - 64)];
    wb[idx] = f2bf(v);
}

__global__ __launch_bounds__(256) void k_scatter(const int* __restrict__ src,
                                                 const int* __restrict__ dst,
                                                 int* __restrict__ cursor,
                                                 int* __restrict__ ssrc, int E) {
    int e = blockIdx.x * 256 + threadIdx.x;
    if (e < E) {
        int pos = atomicAdd(&cursor[dst[e]], 1);
        ssrc[pos] = src[e];
    }
}

// ---- layer-1 aggregation: gather bf16 x rows, mean -> aggb (bf16, N x 128) -
__global__ __launch_bounds__(256) void k_agg1(const unsigned short* __restrict__ xb,
                                              const int* __restrict__ offs,
                                              const int* __restrict__ ssrc,
                                              const float* __restrict__ invd,
                                              unsigned short* __restrict__ aggb,
                                              int n) {
    int node = blockIdx.x * 8 + (threadIdx.x >> 5);
    if (node >= n) return;
    int lane = threadIdx.x & 31;           // 32 lanes x 4 bf16 = 128 feats
    int beg = offs[node], end = offs[node + 1];
    float a0 = 0.f, a1 = 0.f, a2 = 0.f, a3 = 0.f;
    for (int e = beg; e < end; ++e) {
        int s = ssrc[e];
        ushort4 v = *(const ushort4*)(xb + (size_t)s * NFEAT + lane * 4);
        a0 += bf2f(v.x); a1 += bf2f(v.y); a2 += bf2f(v.z); a3 += bf2f(v.w);
    }
    float iv = invd[node];
    ushort4 o;
    o.x = f2bf(a0 * iv); o.y = f2bf(a1 * iv);
    o.z = f2bf(a2 * iv); o.w = f2bf(a3 * iv);
    *(ushort4*)(aggb + (size_t)node * NFEAT + lane * 4) = o;
}

// ---- layer-1 MFMA GEMM: [xb||aggb] @ Wb1 + b1 -> h1, h1r, h1rb -------------
__global__ __launch_bounds__(256) void k_mm1(const unsigned short* __restrict__ xb,
                                             const unsigned short* __restrict__ aggb,
                                             const unsigned short* __restrict__ wb,
                                             const float* __restrict__ bias,
                                             float* __restrict__ h1,
                                             float* __restrict__ h1r,
                                             unsigned short* __restrict__ h1rb,
                                             int M) {
    int wave = threadIdx.x >> 6, lane = threadIdx.x & 63;
    int rowbase = blockIdx.x * 64 + wave * 16;
    f32x4 acc[8];
    #pragma unroll
    for (int ct = 0; ct < 8; ++ct) acc[ct] = (f32x4){0.f, 0.f, 0.f, 0.f};

    int arow = rowbase + (lane & 15);
    if (arow >= M) arow = M - 1;
    int kq = ((lane >> 4) & 3) * 8;

    #pragma unroll 1
    for (int ks = 0; ks < 8; ++ks) {
        const unsigned short* Ap = (ks < 4) ? xb : aggb;
        bf16x8 a = *(const bf16x8*)(Ap + (size_t)arow * 128 + (ks & 3) * 32 + kq);
        const unsigned short* wp = wb + ((size_t)ks * 8 * 64 + lane) * 8;
        #pragma unroll
        for (int ct = 0; ct < 8; ++ct) {
            bf16x8 b = *(const bf16x8*)(wp + (size_t)ct * 512);
            acc[ct] = __builtin_amdgcn_mfma_f32_16x16x32_bf16(a, b, acc[ct], 0, 0, 0);
        }
    }

    int r0 = rowbase + ((lane >> 4) & 3) * 4;
    int col0 = lane & 15;
    #pragma unroll
    for (int ct = 0; ct < 8; ++ct) {
        int col = ct * 16 + col0;
        float bv = bias[col];
        #pragma unroll
        for (int i = 0; i < 4; ++i) {
            int row = r0 + i;
            if (row < M) {
                float v = acc[ct][i] + bv;
                float vr = fmaxf(v, 0.f);
                size_t o = (size_t)row * 128 + col;
                h1[o] = v;
                h1r[o] = vr;
                h1rb[o] = f2bf(vr);
            }
        }
    }
}

// ---- layer-2 MFMA GEMM: h1rb @ [Ws2|Wn2] -> s2 (f32), p2b (bf16) -----------
__global__ __launch_bounds__(256) void k_mm2(const unsigned short* __restrict__ h1rb,
                                             const unsigned short* __restrict__ wb,
                                             float* __restrict__ s2,
                                             unsigned short* __restrict__ p2b,
                                             int M) {
    int wave = threadIdx.x >> 6, lane = threadIdx.x & 63;
    int rowbase = blockIdx.x * 64 + wave * 16;
    f32x4 acc[8];
    #pragma unroll
    for (int ct = 0; ct < 8; ++ct) acc[ct] = (f32x4){0.f, 0.f, 0.f, 0.f};

    int arow = rowbase + (lane & 15);
    if (arow >= M) arow = M - 1;
    int kq = ((lane >> 4) & 3) * 8;

    #pragma unroll 1
    for (int ks = 0; ks < 4; ++ks) {
        bf16x8 a = *(const bf16x8*)(h1rb + (size_t)arow * 128 + ks * 32 + kq);
        const unsigned short* wp = wb + ((size_t)ks * 8 * 64 + lane) * 8;
        #pragma unroll
        for (int ct = 0; ct < 8; ++ct) {
            bf16x8 b = *(const bf16x8*)(wp + (size_t)ct * 512);
            acc[ct] = __builtin_amdgcn_mfma_f32_16x16x32_bf16(a, b, acc[ct], 0, 0, 0);
        }
    }

    int r0 = rowbase + ((lane >> 4) & 3) * 4;
    int col0 = lane & 15;
    #pragma unroll
    for (int ct = 0; ct < 8; ++ct) {
        int col = ct * 16 + col0;
        #pragma unroll
        for (int i = 0; i < 4; ++i) {
            int row = r0 + i;
            if (row < M) {
                float v = acc[ct][i];
                if (col < 64)
                    s2[(size_t)row * 64 + col] = v;
                else
                    p2b[(size_t)row * 64 + (col - 64)] = f2bf(v);
            }
        }
    }
}

// ---- layer-2 aggregation + epilogue: h2 = s2 + inv*sum(p2b[src]) + b2 ------
__global__ __launch_bounds__(256) void k_agg2(const unsigned short* __restrict__ p2b,
                                              const int* __restrict__ offs,
                                              const int* __restrict__ ssrc,
                                              const float* __restrict__ invd,
                                              const float* __restrict__ s2,
                                              const float* __restrict__ b2,
                                              float* __restrict__ h2a,
                                              float* __restrict__ h2b, int n) {
    int node = blockIdx.x * 16 + (threadIdx.x >> 4);
    if (node >= n) return;
    int lane = threadIdx.x & 15;           // 16 lanes x 4 bf16 = 64 feats
    int beg = offs[node], end = offs[node + 1];
    float a0 = 0.f, a1 = 0.f, a2 = 0.f, a3 = 0.f;
    for (int e = beg; e < end; ++e) {
        int s = ssrc[e];
        ushort4 v = *(const ushort4*)(p2b + (size_t)s * 64 + lane * 4);
        a0 += bf2f(v.x); a1 += bf2f(v.y); a2 += bf2f(v.z); a3 += bf2f(v.w);
    }
    float iv = invd[node];
    float4 sv = *(const float4*)(s2 + (size_t)node * 64 + lane * 4);
    float4 bv = *(const float4*)(b2 + lane * 4);
    float4 r = make_float4(sv.x + a0 * iv + bv.x, sv.y + a1 * iv + bv.y,
                           sv.z + a2 * iv + bv.z, sv.w + a3 * iv + bv.w);
    *(float4*)(h2a + (size_t)node * 64 + lane * 4) = r;
    *(float4*)(h2b + (size_t)node * 64 + lane * 4) = r;
}

static inline size_t align256(size_t x) { return (x + 255) & ~(size_t)255; }

extern "C" void kernel_launch(void* const* d_in, const int* in_sizes, int n_in,
                              void* d_out, int out_size, void* d_ws, size_t ws_size,
                              hipStream_t stream) {
    const float* x   = (const float*)d_in[0];
    const float* Ws1 = (const float*)d_in[1];
    const float* Wn1 = (const float*)d_in[2];
    const float* b1  = (const float*)d_in[3];
    const float* Ws2 = (const float*)d_in[4];
    const float* Wn2 = (const float*)d_in[5];
    const float* b2  = (const float*)d_in[6];
    const int* src   = (const int*)d_in[7];
    const int* dst   = (const int*)d_in[8];

    int E = in_sizes[7];
    int N = in_sizes[0] / NFEAT;

    float* out = (float*)d_out;
    float* h2a = out;                         // h2 (copy 1), N x 64
    float* h1  = out + (size_t)N * 64;        // h1, N x 128
    float* h1r = out + (size_t)N * 192;       // relu(h1), N x 128
    float* h2b = out + (size_t)N * 320;       // h2 (copy 2), N x 64

    char* ws = (char*)d_ws;
    size_t off = 0;
    int*   deg    = (int*)(ws + off);  off = align256(off + (size_t)4 * N);
    int*   offs   = (int*)(ws + off);  off = align256(off + (size_t)4 * (N + 1));
    int*   cursor = (int*)(ws + off);  off = align256(off + (size_t)4 * N);
    float* invd   = (float*)(ws + off); off = align256(off + (size_t)4 * N);
    int*   escan  = (int*)(ws + off);  off = align256(off + (size_t)4 * N);
    int*   bsum   = (int*)(ws + off);  off = align256(off + (size_t)4 * 1024);
    int*   ssrc   = (int*)(ws + off);  off = align256(off + (size_t)4 * E);
    unsigned short* wb1 = (unsigned short*)(ws + off); off = align256(off + 2 * 32768);
    unsigned short* wb2 = (unsigned short*)(ws + off); off = align256(off + 2 * 16384);
    // region1: xb (N*128 bf16 = 25.6 MB) aliases s2 (N*64 f32 = 25.6 MB);
    //          xb dead after k_mm1, s2 written by k_mm2.
    unsigned short* xb = (unsigned short*)(ws + off);
    float*          s2 = (float*)(ws + off);
    off = align256(off + (size_t)N * NFEAT * 2);
    // region2: aggb (N*128 bf16) aliases p2b (N*64 bf16);
    //          aggb dead after k_mm1, p2b written by k_mm2.
    unsigned short* aggb = (unsigned short*)(ws + off);
    unsigned short* p2b  = (unsigned short*)(ws + off);
    off = align256(off + (size_t)N * NFEAT * 2);
    unsigned short* h1rb = (unsigned short*)(ws + off);
    off += (size_t)N * NFEAT * 2;

    int nb = (N + 1023) / 1024;

    hipMemsetAsync(deg, 0, (size_t)4 * N, stream);
    k_deg<<<(E + 255) / 256, 256, 0, stream>>>(dst, deg, E);
    k_scan1<<<nb, 256, 0, stream>>>(deg, escan, bsum, N);
    k_scan2<<<1, 1024, 0, stream>>>(bsum, nb);
    k_scan3<<<nb, 256, 0, stream>>>(deg, escan, bsum, offs, cursor, invd, N);
    k_cvt<<<(N * 32 + 255) / 256, 256, 0, stream>>>(x, xb, N * 32);
    k_wprep1<<<128, 256, 0, stream>>>(Ws1, Wn1, wb1);
    k_wprep2<<<64, 256, 0, stream>>>(Ws2, Wn2, wb2);
    k_scatter<<<(E + 255) / 256, 256, 0, stream>>>(src, dst, cursor, ssrc, E);

    k_agg1<<<(N + 7) / 8, 256, 0, stream>>>(xb, offs, ssrc, invd, aggb, N);
    k_mm1<<<(N + 63) / 64, 256, 0, stream>>>(xb, aggb, wb1, b1, h1, h1r, h1rb, N);
    k_mm2<<<(N + 63) / 64, 256, 0, stream>>>(h1rb, wb2, s2, p2b, N);
    k_agg2<<<(N + 15) / 16, 256, 0, stream>>>(p2b, offs, ssrc, invd, s2, b2, h2a, h2b, N);
}